// Round 11
// baseline (56.726 us; speedup 1.0000x reference)
//
#include <hip/hip_runtime.h>

#define TWO_LOG2E 2.8853901817779268f   // 2*log2(e)
#define LOG2E     1.4426950408889634f

typedef float f32x2 __attribute__((ext_vector_type(2)));
typedef float f32x4 __attribute__((ext_vector_type(4)));

// quad_perm DPP cross-lane (VALU pipe)
template<int CTRL>
__device__ __forceinline__ float dpp_qperm(float x) {
    int r = __builtin_amdgcn_update_dpp(0, __float_as_int(x), CTRL, 0xF, 0xF, true);
    return __int_as_float(r);
}

// One thread per (edge, class); lane's class c = tid & 3.
// Weights in LDS (R10: -7%, vmem port freed). R11: class-stride padding kills
// the 4-way ds_read bank conflict (741K in R10), and a 2-stage idx/gather
// pipeline hides HBM idx latency under compute — viable now that compute has
// no vmem weight reloads (R5's pipeline died on the weight-load vmcnt drain).
__global__ __launch_bounds__(256) void edge_mlp(
    const float* __restrict__ m,     // [N_NODES, 4, 2]
    const int*   __restrict__ eidx,  // [2, E]
    const float* __restrict__ W1,    // [4, 4, 8]
    const float* __restrict__ b1,    // [4, 8]
    const float* __restrict__ W2,    // [4, 8, 1]
    const float* __restrict__ b2,    // [4, 1]
    float*       __restrict__ out,   // [E, 4]
    const int nE)
{
    // padded class strides: 36 words (sw1), 18 words (sbw) -> per-wave 4-class
    // reads land in disjoint bank quads (conflict-free broadcast).
    __shared__ __align__(16) float sw1[4 * 36];  // [c][j][i] = W1[c][i][j]*2log2e
    __shared__ __align__(16) float sbw[4 * 18];  // [c][j] = {b1*2log2e, -2*2log2e*W2}
    __shared__ float so0[4];                     // 2log2e*(b2[c] + sum_j W2[c][j])

    const int tidb = threadIdx.x;
    if (tidb < 144) {
        const int c = tidb / 36, r = tidb % 36;
        if (r < 32) {
            const int j = r >> 2, i = r & 3;
            sw1[tidb] = W1[c * 32 + i * 8 + j] * TWO_LOG2E;
        }
    } else if (tidb < 216) {
        const int q = tidb - 144, c = q / 18, r = q % 18;
        if (r < 16) {
            const int j = r >> 1;
            sbw[q] = (r & 1) ? W2[c * 8 + j] * (-2.0f * TWO_LOG2E)
                             : b1[c * 8 + j] * TWO_LOG2E;
        }
    } else if (tidb < 220) {
        const int c = tidb - 216;
        float s = b2[c];
        #pragma unroll
        for (int j = 0; j < 8; ++j) s += W2[c * 8 + j];
        so0[c] = s * TWO_LOG2E;
    }
    __syncthreads();

    const int tid0 = blockIdx.x * blockDim.x + threadIdx.x;
    const int c = tid0 & 3;
    const int cc2 = c * 2;
    const float* w1c = sw1 + c * 36;
    const float* bwc = sbw + c * 18;
    const float o0 = so0[c];

    const int* eidx1 = eidx + nE;
    const int total  = nE * 4;
    const int stride = gridDim.x * blockDim.x;   // multiple of 4 -> c constant
    constexpr int UN = 4;
    const int step = UN * stride;

    int t = tid0;
    f32x2 mc[UN], mr[UN];

    bool have = (t + (UN - 1) * stride < total);
    if (have) {
        int row0[UN], col0[UN];
        #pragma unroll
        for (int k = 0; k < UN; ++k) {
            const int e = (t + k * stride) >> 2;
            row0[k] = __builtin_nontemporal_load(eidx  + e);
            col0[k] = __builtin_nontemporal_load(eidx1 + e);
        }
        #pragma unroll
        for (int k = 0; k < UN; ++k) {
            mc[k] = *(const f32x2*)(m + (unsigned)col0[k] * 8u + cc2);
            mr[k] = *(const f32x2*)(m + (unsigned)row0[k] * 8u + cc2);
        }
    }

    while (have) {
        const int tn = t + step;
        const bool haveN = (tn + (UN - 1) * stride < total);
        int rowN[UN], colN[UN];
        if (haveN) {                      // prefetch next idx (stays in flight:
            #pragma unroll                // compute below only waits on gathers)
            for (int k = 0; k < UN; ++k) {
                const int e = (tn + k * stride) >> 2;
                rowN[k] = __builtin_nontemporal_load(eidx  + e);
                colN[k] = __builtin_nontemporal_load(eidx1 + e);
            }
        }
        // ---- compute current group (LDS weights; no vmem deps but gathers) ----
        #pragma unroll
        for (int k = 0; k < UN; ++k) {
            float o = o0;                          // scaled domain (x 2log2e)
            #pragma unroll
            for (int j = 0; j < 8; j += 2) {       // paired: 1 rcp / 2 j's
                const f32x4 Wa  = *(const f32x4*)(w1c + j * 4);
                const f32x4 Wb  = *(const f32x4*)(w1c + j * 4 + 4);
                const f32x2 bwa = *(const f32x2*)(bwc + j * 2);
                const f32x2 bwb = *(const f32x2*)(bwc + j * 2 + 2);
                float h0 = bwa.x, h1 = bwb.x;
                h0 = fmaf(mc[k].x, Wa.x, h0);  h1 = fmaf(mc[k].x, Wb.x, h1);
                h0 = fmaf(mc[k].y, Wa.y, h0);  h1 = fmaf(mc[k].y, Wb.y, h1);
                h0 = fmaf(mr[k].x, Wa.z, h0);  h1 = fmaf(mr[k].x, Wb.z, h1);
                h0 = fmaf(mr[k].y, Wa.w, h0);  h1 = fmaf(mr[k].y, Wb.w, h1);
                const float a0 = __builtin_amdgcn_exp2f(h0) + 1.0f;   // 1+e^{2x}
                const float a1 = __builtin_amdgcn_exp2f(h1) + 1.0f;
                const float inv = __builtin_amdgcn_rcpf(a0 * a1);
                o = fmaf(bwa.y, inv * a1, o);      // w2n0 * r0
                o = fmaf(bwb.y, inv * a0, o);      // w2n1 * r1
            }
            const float e2 = __builtin_amdgcn_exp2f(o);
            const float r2 = __builtin_amdgcn_rcpf(e2 + 1.0f);
            const float y  = fmaf(-2.0f, r2, 1.0f);       // tanh(o_true), |y|<1
            // e^y via deg-6 Taylor (abs err ~2e-4)
            float p = fmaf(y, 0.0013888889f, 0.0083333333f);
            p = fmaf(p, y, 0.0416666667f);
            p = fmaf(p, y, 0.1666666667f);
            p = fmaf(p, y, 0.5f);
            p = fmaf(p, y, 1.0f);
            p = fmaf(p, y, 1.0f);
            float s = p + dpp_qperm<0xB1>(p);      // quad softmax denom
            s = s + dpp_qperm<0x4E>(s);
            __builtin_nontemporal_store(p * __builtin_amdgcn_rcpf(s),
                                        out + (t + k * stride));
        }
        if (haveN) {                      // idx arrived during compute; gathers
            #pragma unroll                // now hide under next iter's front
            for (int k = 0; k < UN; ++k) {
                mc[k] = *(const f32x2*)(m + (unsigned)colN[k] * 8u + cc2);
                mr[k] = *(const f32x2*)(m + (unsigned)rowN[k] * 8u + cc2);
            }
        }
        t = tn;
        have = haveN;
    }

    // tail
    for (; t < total; t += stride) {
        const int e  = t >> 2;
        const int r0 = eidx[e];
        const int c0 = eidx1[e];
        const f32x2 mcv = *(const f32x2*)(m + (unsigned)c0 * 8u + cc2);
        const f32x2 mrv = *(const f32x2*)(m + (unsigned)r0 * 8u + cc2);
        float o = o0;
        #pragma unroll
        for (int j = 0; j < 8; j += 2) {
            const f32x4 Wa  = *(const f32x4*)(w1c + j * 4);
            const f32x4 Wb  = *(const f32x4*)(w1c + j * 4 + 4);
            const f32x2 bwa = *(const f32x2*)(bwc + j * 2);
            const f32x2 bwb = *(const f32x2*)(bwc + j * 2 + 2);
            float h0 = bwa.x, h1 = bwb.x;
            h0 = fmaf(mcv.x, Wa.x, h0);  h1 = fmaf(mcv.x, Wb.x, h1);
            h0 = fmaf(mcv.y, Wa.y, h0);  h1 = fmaf(mcv.y, Wb.y, h1);
            h0 = fmaf(mrv.x, Wa.z, h0);  h1 = fmaf(mrv.x, Wb.z, h1);
            h0 = fmaf(mrv.y, Wa.w, h0);  h1 = fmaf(mrv.y, Wb.w, h1);
            const float a0 = __builtin_amdgcn_exp2f(h0) + 1.0f;
            const float a1 = __builtin_amdgcn_exp2f(h1) + 1.0f;
            const float inv = __builtin_amdgcn_rcpf(a0 * a1);
            o = fmaf(bwa.y, inv * a1, o);
            o = fmaf(bwb.y, inv * a0, o);
        }
        const float e2 = __builtin_amdgcn_exp2f(o);
        const float r2 = __builtin_amdgcn_rcpf(e2 + 1.0f);
        const float y  = fmaf(-2.0f, r2, 1.0f);
        float p = fmaf(y, 0.0013888889f, 0.0083333333f);
        p = fmaf(p, y, 0.0416666667f);
        p = fmaf(p, y, 0.1666666667f);
        p = fmaf(p, y, 0.5f);
        p = fmaf(p, y, 1.0f);
        p = fmaf(p, y, 1.0f);
        float s = p + dpp_qperm<0xB1>(p);
        s = s + dpp_qperm<0x4E>(s);
        out[t] = p * __builtin_amdgcn_rcpf(s);
    }
}

extern "C" void kernel_launch(void* const* d_in, const int* in_sizes, int n_in,
                              void* d_out, int out_size, void* d_ws, size_t ws_size,
                              hipStream_t stream) {
    const float* m  = (const float*)d_in[0];
    const int* eidx = (const int*)d_in[1];
    const float* W1 = (const float*)d_in[2];
    const float* b1 = (const float*)d_in[3];
    const float* W2 = (const float*)d_in[4];
    const float* b2 = (const float*)d_in[5];
    float* out = (float*)d_out;
    const int nE = in_sizes[1] / 2;

    const int threads = 256;
    const int blocks  = 2048;
    hipLaunchKernelGGL(edge_mlp, dim3(blocks), dim3(threads), 0, stream,
                       m, eidx, W1, b1, W2, b2, out, nE);
}

// Round 12
// 54.806 us; speedup vs baseline: 1.0350x; 1.0350x over previous
//
#include <hip/hip_runtime.h>

#define TWO_LOG2E 2.8853901817779268f   // 2*log2(e)
#define LOG2E     1.4426950408889634f

typedef float f32x2 __attribute__((ext_vector_type(2)));

// quad_perm DPP cross-lane (VALU pipe)
template<int CTRL>
__device__ __forceinline__ float dpp_qperm(float x) {
    int r = __builtin_amdgcn_update_dpp(0, __float_as_int(x), CTRL, 0xF, 0xF, true);
    return __int_as_float(r);
}

__device__ __forceinline__ f32x2 splat2(float s) { f32x2 v; v.x = s; v.y = s; return v; }

// One thread per (edge, class); lane's class c = tid & 3. Weights in LDS
// (R10 win), padded strides (R11: conflicts=0). R12: issue diet —
// layer-1 as packed f32x2 FMA (v_pk_fma_f32: 32->16 issues), softmax
// numerator back to 1x exp2 (Taylor's 6-deep FMA chain was worse).
// Also a discriminating probe: if dur stays ~56us while VALUBusy drops,
// the kernel is vmem-request(TA)-bound, not compute-bound.
__global__ __launch_bounds__(256) void edge_mlp(
    const float* __restrict__ m,     // [N_NODES, 4, 2]
    const int*   __restrict__ eidx,  // [2, E]
    const float* __restrict__ W1,    // [4, 4, 8]
    const float* __restrict__ b1,    // [4, 8]
    const float* __restrict__ W2,    // [4, 8, 1]
    const float* __restrict__ b2,    // [4, 1]
    float*       __restrict__ out,   // [E, 4]
    const int nE)
{
    // sw1[c][p][i] = f32x2 {W1[c][i][2p], W1[c][i][2p+1]} * 2log2e
    // class stride 36 floats -> 4 class addrs at banks {4c..} disjoint.
    __shared__ __align__(16) float sw1[4 * 36];
    // sbw[c][p] = {bb01 (f32x2), w2n01 (f32x2)}; class stride 18 floats.
    __shared__ __align__(16) float sbw[4 * 18];
    __shared__ float so0[4];         // 2log2e*(b2[c] + sum_j W2[c][j])

    const int tidb = threadIdx.x;
    if (tidb < 128) {                // (c,i,j) -> paired layout
        const int c = tidb >> 5, r = tidb & 31, i = r >> 3, j = r & 7;
        sw1[c * 36 + (j >> 1) * 8 + i * 2 + (j & 1)] =
            W1[c * 32 + i * 8 + j] * TWO_LOG2E;
    } else if (tidb < 192) {
        const int q = tidb - 128, c = q >> 4, r = q & 15, p = r >> 2, k = r & 3;
        const int j = 2 * p + (k & 1);
        sbw[c * 18 + p * 4 + k] =
            (k < 2) ? b1[c * 8 + j] * TWO_LOG2E
                    : W2[c * 8 + j] * (-2.0f * TWO_LOG2E);
    } else if (tidb < 196) {
        const int c = tidb - 192;
        float s = b2[c];
        #pragma unroll
        for (int j = 0; j < 8; ++j) s += W2[c * 8 + j];
        so0[c] = s * TWO_LOG2E;
    }
    __syncthreads();

    const int tid0 = blockIdx.x * blockDim.x + threadIdx.x;
    const int c = tid0 & 3;
    const int cc2 = c * 2;
    const float* w1c = sw1 + c * 36;
    const f32x2* bwc = (const f32x2*)(sbw + c * 18);
    const float o0 = so0[c];

    const int* eidx1 = eidx + nE;
    const int total  = nE * 4;
    const int stride = gridDim.x * blockDim.x;   // multiple of 4 -> c constant

    constexpr int UN = 4;
    int t = tid0;

    for (; t + (UN - 1) * stride < total; t += UN * stride) {
        int row[UN], col[UN];
        #pragma unroll
        for (int k = 0; k < UN; ++k) {
            const int e = (t + k * stride) >> 2;
            row[k] = __builtin_nontemporal_load(eidx  + e);
            col[k] = __builtin_nontemporal_load(eidx1 + e);
        }
        f32x2 mc[UN], mr[UN];
        #pragma unroll
        for (int k = 0; k < UN; ++k) {
            mc[k] = *(const f32x2*)(m + (unsigned)col[k] * 8u + cc2);
            mr[k] = *(const f32x2*)(m + (unsigned)row[k] * 8u + cc2);
        }
        #pragma unroll
        for (int k = 0; k < UN; ++k) {
            float o = o0;                          // scaled domain (x 2log2e)
            #pragma unroll
            for (int p = 0; p < 4; ++p) {          // j-pair p: packed layer-1
                const f32x2* wp = (const f32x2*)(w1c + p * 8);
                f32x2 h = bwc[p * 2];              // bb01
                h = __builtin_elementwise_fma(splat2(mc[k].x), wp[0], h);
                h = __builtin_elementwise_fma(splat2(mc[k].y), wp[1], h);
                h = __builtin_elementwise_fma(splat2(mr[k].x), wp[2], h);
                h = __builtin_elementwise_fma(splat2(mr[k].y), wp[3], h);
                const float a0 = __builtin_amdgcn_exp2f(h.x) + 1.0f; // 1+e^{2x}
                const float a1 = __builtin_amdgcn_exp2f(h.y) + 1.0f;
                const float inv = __builtin_amdgcn_rcpf(a0 * a1);
                const f32x2 w2n01 = bwc[p * 2 + 1];
                o = fmaf(w2n01.x, inv * a1, o);    // tanh0 * w2_0 (folded)
                o = fmaf(w2n01.y, inv * a0, o);    // tanh1 * w2_1
            }
            const float e2 = __builtin_amdgcn_exp2f(o);
            const float r2 = __builtin_amdgcn_rcpf(e2 + 1.0f);
            // eo = e^{tanh(o_true)} = 2^{LOG2E - TWO_LOG2E*r2}
            const float eo = __builtin_amdgcn_exp2f(fmaf(-TWO_LOG2E, r2, LOG2E));
            float s = eo + dpp_qperm<0xB1>(eo);    // quad softmax denom
            s = s + dpp_qperm<0x4E>(s);
            __builtin_nontemporal_store(eo * __builtin_amdgcn_rcpf(s),
                                        out + (t + k * stride));
        }
    }

    // tail
    for (; t < total; t += stride) {
        const int e  = t >> 2;
        const int r0 = eidx[e];
        const int c0 = eidx1[e];
        const f32x2 mcv = *(const f32x2*)(m + (unsigned)c0 * 8u + cc2);
        const f32x2 mrv = *(const f32x2*)(m + (unsigned)r0 * 8u + cc2);
        float o = o0;
        #pragma unroll
        for (int p = 0; p < 4; ++p) {
            const f32x2* wp = (const f32x2*)(w1c + p * 8);
            f32x2 h = bwc[p * 2];
            h = __builtin_elementwise_fma(splat2(mcv.x), wp[0], h);
            h = __builtin_elementwise_fma(splat2(mcv.y), wp[1], h);
            h = __builtin_elementwise_fma(splat2(mrv.x), wp[2], h);
            h = __builtin_elementwise_fma(splat2(mrv.y), wp[3], h);
            const float a0 = __builtin_amdgcn_exp2f(h.x) + 1.0f;
            const float a1 = __builtin_amdgcn_exp2f(h.y) + 1.0f;
            const float inv = __builtin_amdgcn_rcpf(a0 * a1);
            const f32x2 w2n01 = bwc[p * 2 + 1];
            o = fmaf(w2n01.x, inv * a1, o);
            o = fmaf(w2n01.y, inv * a0, o);
        }
        const float e2 = __builtin_amdgcn_exp2f(o);
        const float r2 = __builtin_amdgcn_rcpf(e2 + 1.0f);
        const float eo = __builtin_amdgcn_exp2f(fmaf(-TWO_LOG2E, r2, LOG2E));
        float s = eo + dpp_qperm<0xB1>(eo);
        s = s + dpp_qperm<0x4E>(s);
        out[t] = eo * __builtin_amdgcn_rcpf(s);
    }
}

extern "C" void kernel_launch(void* const* d_in, const int* in_sizes, int n_in,
                              void* d_out, int out_size, void* d_ws, size_t ws_size,
                              hipStream_t stream) {
    const float* m  = (const float*)d_in[0];
    const int* eidx = (const int*)d_in[1];
    const float* W1 = (const float*)d_in[2];
    const float* b1 = (const float*)d_in[3];
    const float* W2 = (const float*)d_in[4];
    const float* b2 = (const float*)d_in[5];
    float* out = (float*)d_out;
    const int nE = in_sizes[1] / 2;

    const int threads = 256;
    const int blocks  = 2048;
    hipLaunchKernelGGL(edge_mlp, dim3(blocks), dim3(threads), 0, stream,
                       m, eidx, W1, b1, W2, b2, out, nE);
}